// Round 1
// baseline (892.710 us; speedup 1.0000x reference)
//
#include <hip/hip_runtime.h>
#include <math.h>

#define BB  16
#define TT  1024
#define NN  128
#define WIN 30
#define NWD 498          // number of windows
#define DM  256          // D_MODEL
#define IND 384          // 3*N

#define INV_W (1.0f/498.0f)

// workspace offsets in floats
#define OFF_MU    0
#define OFF_RSTD  (OFF_MU   + BB*NWD*NN)
#define OFF_SUMLO (OFF_RSTD + BB*NWD*NN)
#define OFF_CM2   (OFF_SUMLO + BB*NN*NN)
#define OFF_CM4   (OFF_CM2  + BB*NN*NN)
#define OFF_CM8   (OFF_CM4  + BB*NN*NN)
#define OFF_ASUM  (OFF_CM8  + BB*NN*NN)
#define OFF_ANORM (OFF_ASUM + BB*NN*NN)
#define OFF_X     (OFF_ANORM + BB*NN*NN)
#define OFF_BUFA  (OFF_X    + BB*NN*IND)
#define OFF_BUFB  (OFF_BUFA + BB*NN*DM)

// ---------------------------------------------------------------- K1: per-window channel stats
__global__ __launch_bounds__(128) void k1_stats(const float* __restrict__ x, float* __restrict__ ws) {
    int bw = blockIdx.x;            // b*NWD + w
    int b = bw / NWD, w = bw - b*NWD;
    int n = threadIdx.x;
    int s = w * 2;
    const float* xp = x + ((size_t)(b*TT + s))*NN + n;
    float sum = 0.f;
#pragma unroll
    for (int t = 0; t < WIN; ++t) sum += xp[t*NN];
    float mean = sum * (1.0f/30.0f);
    float ss = 0.f;
#pragma unroll
    for (int t = 0; t < WIN; ++t) { float d = xp[t*NN] - mean; ss += d*d; }
    float var = fmaxf(ss * (1.0f/29.0f), 1e-8f);
    float r = 1.0f / sqrtf(var);
    ws[OFF_MU   + bw*NN + n] = mean;
    // fold 1/sqrt(29) so corr(i,j) = sum_t y_i y_j directly
    ws[OFF_RSTD + bw*NN + n] = r * 0.185695338f;
}

// stage one normalized window (30 x 128) into LDS; blockDim must be 256
__device__ __forceinline__ void stage_window(const float* __restrict__ x, const float* __restrict__ ws,
                                             int b, int w, int tid, float y[WIN][NN+4]) {
    int s = w * 2;
    const float4* xr  = (const float4*)(x + (size_t)(b*TT + s)*NN);
    const float4* mu4 = (const float4*)(ws + OFF_MU   + (size_t)(b*NWD + w)*NN);
    const float4* rs4 = (const float4*)(ws + OFF_RSTD + (size_t)(b*NWD + w)*NN);
    for (int idx = tid; idx < WIN*32; idx += 256) {
        int t = idx >> 5, c4 = idx & 31;
        float4 xv = xr[t*32 + c4];
        float4 m  = mu4[c4];
        float4 rv = rs4[c4];
        float4 o;
        o.x = (xv.x - m.x) * rv.x;
        o.y = (xv.y - m.y) * rv.y;
        o.z = (xv.z - m.z) * rv.z;
        o.w = (xv.w - m.w) * rv.w;
        *(float4*)&y[t][c4*4] = o;
    }
}

// ---------------------------------------------------------------- K2: sum of corr over windows
__global__ __launch_bounds__(256) void k2_sumcorr(const float* __restrict__ x, float* __restrict__ ws) {
    __shared__ __align__(16) float y[WIN][NN+4];
    int b = blockIdx.x >> 4, wc = blockIdx.x & 15;
    int w0 = wc*32, w1 = min(NWD, w0+32);
    int tid = threadIdx.x;
    int i0 = (tid >> 4)*8, j0 = (tid & 15)*8;
    float acc[8][8];
#pragma unroll
    for (int p=0;p<8;++p)
#pragma unroll
        for (int q=0;q<8;++q) acc[p][q] = 0.f;

    for (int w = w0; w < w1; ++w) {
        __syncthreads();
        stage_window(x, ws, b, w, tid, y);
        __syncthreads();
#pragma unroll 6
        for (int t = 0; t < WIN; ++t) {
            float4 a0 = *(const float4*)&y[t][i0];
            float4 a1 = *(const float4*)&y[t][i0+4];
            float4 b0 = *(const float4*)&y[t][j0];
            float4 b1 = *(const float4*)&y[t][j0+4];
            float av[8] = {a0.x,a0.y,a0.z,a0.w,a1.x,a1.y,a1.z,a1.w};
            float bv[8] = {b0.x,b0.y,b0.z,b0.w,b1.x,b1.y,b1.z,b1.w};
#pragma unroll
            for (int p=0;p<8;++p)
#pragma unroll
                for (int q=0;q<8;++q) acc[p][q] = fmaf(av[p], bv[q], acc[p][q]);
        }
    }
    float nwf = (float)(w1 - w0);
    float* sl = ws + OFF_SUMLO + (size_t)b*NN*NN;
#pragma unroll
    for (int p=0;p<8;++p)
#pragma unroll
        for (int q=0;q<8;++q) {
            int gi = i0+p, gj = j0+q;
            float v = (gi==gj) ? nwf : acc[p][q];   // diag of corr is forced to 1 per window
            atomicAdd(&sl[gi*NN+gj], v);
        }
}

// ---------------------------------------------------------------- K4: centered moments d=2,4,8
__global__ __launch_bounds__(256, 1) void k4_moments(const float* __restrict__ x, float* __restrict__ ws) {
    __shared__ __align__(16) float y[WIN][NN+4];
    int b = blockIdx.x >> 4, wc = blockIdx.x & 15;
    int w0 = wc*32, w1 = min(NWD, w0+32);
    int tid = threadIdx.x;
    int i0 = (tid >> 4)*8, j0 = (tid & 15)*8;
    const float* sl = ws + OFF_SUMLO + (size_t)b*NN*NN;
    float mv[8][8], s2[8][8], s4[8][8], s8[8][8];
#pragma unroll
    for (int p=0;p<8;++p)
#pragma unroll
        for (int q=0;q<8;++q) {
            mv[p][q] = sl[(i0+p)*NN + j0+q] * INV_W;
            s2[p][q] = 0.f; s4[p][q] = 0.f; s8[p][q] = 0.f;
        }

    for (int w = w0; w < w1; ++w) {
        __syncthreads();
        stage_window(x, ws, b, w, tid, y);
        __syncthreads();
        float dot[8][8];
#pragma unroll
        for (int p=0;p<8;++p)
#pragma unroll
            for (int q=0;q<8;++q) dot[p][q] = 0.f;
#pragma unroll 2
        for (int t = 0; t < WIN; ++t) {
            float4 a0 = *(const float4*)&y[t][i0];
            float4 a1 = *(const float4*)&y[t][i0+4];
            float4 b0 = *(const float4*)&y[t][j0];
            float4 b1 = *(const float4*)&y[t][j0+4];
            float av[8] = {a0.x,a0.y,a0.z,a0.w,a1.x,a1.y,a1.z,a1.w};
            float bv[8] = {b0.x,b0.y,b0.z,b0.w,b1.x,b1.y,b1.z,b1.w};
#pragma unroll
            for (int p=0;p<8;++p)
#pragma unroll
                for (int q=0;q<8;++q) dot[p][q] = fmaf(av[p], bv[q], dot[p][q]);
        }
#pragma unroll
        for (int p=0;p<8;++p)
#pragma unroll
            for (int q=0;q<8;++q) {
                float c = dot[p][q] - mv[p][q];
                float p2 = c*c, p4 = p2*p2;
                s2[p][q] += p2; s4[p][q] += p4; s8[p][q] += p4*p4;
            }
    }
    float nwf = (float)(w1 - w0);
#pragma unroll
    for (int p=0;p<8;++p)
#pragma unroll
        for (int q=0;q<8;++q) {
            int gi = i0+p, gj = j0+q;
            float a2 = s2[p][q], a4 = s4[p][q], a8 = s8[p][q];
            if (gi == gj) {   // corr diag == 1 exactly every window
                float c = 1.0f - mv[p][q];
                float p2 = c*c, p4 = p2*p2, p8 = p4*p4;
                a2 = nwf*p2; a4 = nwf*p4; a8 = nwf*p8;
            }
            atomicAdd(&ws[OFF_CM2 + (size_t)b*NN*NN + gi*NN+gj], a2);
            atomicAdd(&ws[OFF_CM4 + (size_t)b*NN*NN + gi*NN+gj], a4);
            atomicAdd(&ws[OFF_CM8 + (size_t)b*NN*NN + gi*NN+gj], a8);
        }
}

// ---------------------------------------------------------------- K5: rowwise_corr per (b, d), accumulate A_sum
__global__ __launch_bounds__(256) void k5_rowcorr(float* __restrict__ ws) {
    __shared__ float Xc[NN][NN+1];
    __shared__ float rmn[NN];
    __shared__ float iden[NN];
    int b = blockIdx.x / 3, di = blockIdx.x % 3;
    const float* cm = ws + (di==0 ? OFF_CM2 : (di==1 ? OFF_CM4 : OFF_CM8)) + (size_t)b*NN*NN;
    int tid = threadIdx.x;
    for (int idx = tid; idx < NN*NN; idx += 256) {
        int n = idx >> 7, f = idx & 127;
        Xc[n][f] = cm[idx] * INV_W;
    }
    __syncthreads();
    if (tid < NN) {
        float s = 0.f;
        for (int f = 0; f < NN; ++f) s += Xc[tid][f];
        rmn[tid] = s * (1.0f/NN);
    }
    __syncthreads();
    for (int idx = tid; idx < NN*NN; idx += 256) {
        int n = idx >> 7, f = idx & 127;
        Xc[n][f] -= rmn[n];
    }
    __syncthreads();
    int n0 = (tid >> 4)*8, m0 = (tid & 15)*8;
    float acc[8][8];
#pragma unroll
    for (int k=0;k<8;++k)
#pragma unroll
        for (int l=0;l<8;++l) acc[k][l] = 0.f;
    for (int f = 0; f < NN; ++f) {
        float an[8], am[8];
#pragma unroll
        for (int k=0;k<8;++k) { an[k] = Xc[n0+k][f]; am[k] = Xc[m0+k][f]; }
#pragma unroll
        for (int k=0;k<8;++k)
#pragma unroll
            for (int l=0;l<8;++l) acc[k][l] = fmaf(an[k], am[l], acc[k][l]);
    }
    if (n0 == m0) {
#pragma unroll
        for (int k=0;k<8;++k) iden[n0+k] = 1.0f/sqrtf(fmaxf(acc[k][k], 1e-8f));
    }
    __syncthreads();
    float* As = ws + OFF_ASUM + (size_t)b*NN*NN;
#pragma unroll
    for (int k=0;k<8;++k)
#pragma unroll
        for (int l=0;l<8;++l) {
            int gi = n0+k, gj = m0+l;
            float v = acc[k][l]*iden[gi]*iden[gj];
            if (gi == gj) v = 1.0f;
            atomicAdd(&As[gi*NN+gj], v);
        }
}

// ---------------------------------------------------------------- K6: symmetrize + normalize adjacency
__global__ __launch_bounds__(256) void k6_anorm(float* __restrict__ ws) {
    __shared__ float As[NN][NN+1];
    __shared__ float dis[NN];
    int b = blockIdx.x;
    const float* Asum = ws + OFF_ASUM + (size_t)b*NN*NN;
    int tid = threadIdx.x;
    for (int idx = tid; idx < NN*NN; idx += 256) {
        int n = idx >> 7, m = idx & 127;
        As[n][m] = (Asum[n*NN+m] + Asum[m*NN+n]) * (1.0f/6.0f);  // mean-of-3 then 0.5*(A+A^T)
    }
    __syncthreads();
    if (tid < NN) {
        float d = 1.0f;                       // +I diag
        for (int m = 0; m < NN; ++m) d += As[tid][m];
        dis[tid] = sqrtf(1.0f / fmaxf(d, 1e-8f));
    }
    __syncthreads();
    float* An = ws + OFF_ANORM + (size_t)b*NN*NN;
    for (int idx = tid; idx < NN*NN; idx += 256) {
        int n = idx >> 7, m = idx & 127;
        float v = As[n][m] + (n==m ? 1.0f : 0.0f);
        An[idx] = v * dis[n] * dis[m];
    }
}

// ---------------------------------------------------------------- K7: build X (concat cm2,4,8) + layernorm
__global__ __launch_bounds__(128) void k7_ln(const float* __restrict__ gamma, const float* __restrict__ beta,
                                             float* __restrict__ ws) {
    __shared__ float red[128];
    int row = blockIdx.x;   // b*NN + n
    int tid = threadIdx.x;
    float v0 = ws[OFF_CM2 + (size_t)row*NN + tid] * INV_W;
    float v1 = ws[OFF_CM4 + (size_t)row*NN + tid] * INV_W;
    float v2 = ws[OFF_CM8 + (size_t)row*NN + tid] * INV_W;
    red[tid] = v0+v1+v2;
    __syncthreads();
    for (int o = 64; o > 0; o >>= 1) { if (tid < o) red[tid] += red[tid+o]; __syncthreads(); }
    float mean = red[0] * (1.0f/IND);
    __syncthreads();
    float d0 = v0-mean, d1 = v1-mean, d2 = v2-mean;
    red[tid] = d0*d0 + d1*d1 + d2*d2;
    __syncthreads();
    for (int o = 64; o > 0; o >>= 1) { if (tid < o) red[tid] += red[tid+o]; __syncthreads(); }
    float rstd = 1.0f / sqrtf(red[0]*(1.0f/IND) + 1e-5f);
    float* X = ws + OFF_X + (size_t)row*IND;
    X[tid]     = d0*rstd*gamma[tid]     + beta[tid];
    X[tid+128] = d1*rstd*gamma[tid+128] + beta[tid+128];
    X[tid+256] = d2*rstd*gamma[tid+256] + beta[tid+256];
}

// ---------------------------------------------------------------- K8: dense (rows x K) @ (K x 256) + bias
__global__ __launch_bounds__(256) void k8_gemm(const float* __restrict__ Wt, const float* __restrict__ bias,
                                               const float* __restrict__ in, float* __restrict__ out, int K) {
    __shared__ float Xs[8][IND];
    int r0 = blockIdx.x * 8;
    int tid = threadIdx.x;
    for (int r = 0; r < 8; ++r)
        for (int c = tid; c < K; c += 256)
            Xs[r][c] = in[(size_t)(r0+r)*K + c];
    __syncthreads();
    float acc[8];
#pragma unroll
    for (int r = 0; r < 8; ++r) acc[r] = bias[tid];
    for (int k = 0; k < K; ++k) {
        float wv = Wt[(size_t)k*DM + tid];
#pragma unroll
        for (int r = 0; r < 8; ++r) acc[r] = fmaf(Xs[r][k], wv, acc[r]);
    }
#pragma unroll
    for (int r = 0; r < 8; ++r) out[(size_t)(r0+r)*DM + tid] = acc[r];
}

// ---------------------------------------------------------------- K9: H = relu(A_norm @ Z)
__global__ __launch_bounds__(256) void k9_prop(const float* __restrict__ Anorm, const float* __restrict__ Zin,
                                               float* __restrict__ out) {
    __shared__ float Ar[8][NN];
    int bx = blockIdx.x;
    int b = bx >> 4, n0 = (bx & 15)*8;
    int tid = threadIdx.x;
    const float* A = Anorm + (size_t)b*NN*NN;
    if (tid < NN) {
#pragma unroll
        for (int r = 0; r < 8; ++r) Ar[r][tid] = A[(n0+r)*NN + tid];
    }
    __syncthreads();
    float acc[8] = {0,0,0,0,0,0,0,0};
    const float* Z = Zin + (size_t)b*NN*DM;
    for (int m = 0; m < NN; ++m) {
        float z = Z[(size_t)m*DM + tid];
#pragma unroll
        for (int r = 0; r < 8; ++r) acc[r] = fmaf(Ar[r][m], z, acc[r]);
    }
    float* O = out + (size_t)b*NN*DM;
#pragma unroll
    for (int r = 0; r < 8; ++r) O[(size_t)(n0+r)*DM + tid] = fmaxf(acc[r], 0.0f);
}

// ---------------------------------------------------------------- K12: mean-pool + sigmoid head
__global__ __launch_bounds__(256) void k12_head(const float* __restrict__ H, const float* __restrict__ Wc,
                                                const float* __restrict__ bc, float* __restrict__ outp) {
    __shared__ float red[256];
    int b = blockIdx.x, tid = threadIdx.x;
    float s = 0.f;
    for (int n = 0; n < NN; ++n) s += H[((size_t)b*NN+n)*DM + tid];
    red[tid] = s * (1.0f/NN) * Wc[tid];
    __syncthreads();
    for (int o = 128; o > 0; o >>= 1) { if (tid < o) red[tid] += red[tid+o]; __syncthreads(); }
    if (tid == 0) outp[b] = 1.0f/(1.0f + expf(-(red[0] + bc[0])));
}

// ----------------------------------------------------------------
extern "C" void kernel_launch(void* const* d_in, const int* in_sizes, int n_in,
                              void* d_out, int out_size, void* d_ws, size_t ws_size,
                              hipStream_t stream) {
    (void)in_sizes; (void)n_in; (void)out_size; (void)ws_size;
    const float* x     = (const float*)d_in[0];
    const float* gamma = (const float*)d_in[1];
    const float* beta  = (const float*)d_in[2];
    const float* W1    = (const float*)d_in[3];
    const float* b1    = (const float*)d_in[4];
    const float* W2    = (const float*)d_in[5];
    const float* b2    = (const float*)d_in[6];
    const float* Wc    = (const float*)d_in[7];
    const float* bc    = (const float*)d_in[8];
    float* ws  = (float*)d_ws;
    float* out = (float*)d_out;

    // zero the atomic accumulators (sumlo, cm2, cm4, cm8, Asum are contiguous)
    hipMemsetAsync(ws + OFF_SUMLO, 0, (size_t)(5*BB*NN*NN)*sizeof(float), stream);

    k1_stats  <<<BB*NWD, 128, 0, stream>>>(x, ws);
    k2_sumcorr<<<BB*16,  256, 0, stream>>>(x, ws);
    k4_moments<<<BB*16,  256, 0, stream>>>(x, ws);
    k5_rowcorr<<<BB*3,   256, 0, stream>>>(ws);
    k6_anorm  <<<BB,     256, 0, stream>>>(ws);
    k7_ln     <<<BB*NN,  128, 0, stream>>>(gamma, beta, ws);
    k8_gemm   <<<BB*NN/8,256, 0, stream>>>(W1, b1, ws + OFF_X,    ws + OFF_BUFA, IND);
    k9_prop   <<<BB*16,  256, 0, stream>>>(ws + OFF_ANORM, ws + OFF_BUFA, ws + OFF_BUFB);
    k8_gemm   <<<BB*NN/8,256, 0, stream>>>(W2, b2, ws + OFF_BUFB, ws + OFF_BUFA, DM);
    k9_prop   <<<BB*16,  256, 0, stream>>>(ws + OFF_ANORM, ws + OFF_BUFA, ws + OFF_BUFB);
    k12_head  <<<BB,     256, 0, stream>>>(ws + OFF_BUFB, Wc, bc, out);
}